// Round 6
// baseline (1126.277 us; speedup 1.0000x reference)
//
#include <hip/hip_runtime.h>
#include <hip/hip_fp16.h>
#include <math.h>

#define N_NODES 50000
#define N_EDGES 1600000
#define HID 256
#define NBIN 8                 // src-range bins (slice = 6250 nodes = 1.6MB of h8)
#define BINW 6250              // N_NODES / NBIN
#define M2 (N_NODES * NBIN)    // 400000 (dst,bin) counters
#define SB2 ((M2 + 255) / 256) // 1563 scan blocks
#define V2_NODES 128           // nodes per aggr2 block (64KB LDS accum)
#define V2_GRID ((N_NODES + V2_NODES - 1) / V2_NODES)  // 391 — all co-resident
// eps = 0

typedef _Float16 f16x8 __attribute__((ext_vector_type(8)));
typedef float f32x4 __attribute__((ext_vector_type(4)));
typedef float v2f __attribute__((ext_vector_type(2)));

// ROCm 7.2 has no __hmax2 — emit v_pk_max_f16 directly.
static __device__ __forceinline__ __half2 pk_max2(__half2 a, __half2 b) {
    unsigned au = *reinterpret_cast<unsigned*>(&a);
    unsigned bu = *reinterpret_cast<unsigned*>(&b);
    unsigned r;
    asm("v_pk_max_f16 %0, %1, %2" : "=v"(r) : "v"(au), "v"(bu));
    return *reinterpret_cast<__half2*>(&r);
}

// half2 held as a raw dword (for VOP3P inline asm operands)
static __device__ __forceinline__ unsigned h2u(float lo, float hi) {
    __half2 t = __floats2half2_rn(lo, hi);
    return *reinterpret_cast<unsigned*>(&t);
}

static __device__ __forceinline__ __half2 u2h(unsigned u) {
    return *reinterpret_cast<__half2*>(&u);
}
static __device__ __forceinline__ unsigned h2bits(__half2 h) {
    return *reinterpret_cast<unsigned*>(&h);
}

// packed fp16 FMA with the LOW half of ATTR broadcast to both result halves
#define PKFMA_LO(ACC, ATTR, W)                                           \
    asm("v_pk_fma_f16 %0, %1, %2, %0 op_sel:[0,0,0] op_sel_hi:[0,1,1]"   \
        : "+v"(ACC) : "v"(ATTR), "v"(W))
// packed fp16 FMA with the HIGH half of ATTR broadcast to both result halves
#define PKFMA_HI(ACC, ATTR, W)                                           \
    asm("v_pk_fma_f16 %0, %1, %2, %0 op_sel:[1,0,0] op_sel_hi:[1,1,1]"   \
        : "+v"(ACC) : "v"(ATTR), "v"(W))

// 4 floats -> 4 fp8 (e4m3) packed in one dword
static __device__ __forceinline__ unsigned pack4_fp8(float a, float b, float c, float d) {
    int v = __builtin_amdgcn_cvt_pk_fp8_f32(a, b, 0, false);
    v = __builtin_amdgcn_cvt_pk_fp8_f32(c, d, v, true);
    return (unsigned)v;
}

// ---------------------------------------------------------------- CSR build ---
// counters indexed dst*NBIN + src/BINW -> records sorted (dst, src-bin)
__global__ __launch_bounds__(256) void hist_kernel(const int* __restrict__ src,
                                                   const int* __restrict__ dst,
                                                   int* __restrict__ deg2) {
    const int T = gridDim.x * 256;
    const int t = blockIdx.x * 256 + threadIdx.x;
#pragma unroll
    for (int i = 0; i < 4; ++i) {
        int e = t + i * T;
        if (e < N_EDGES) {
            int d = dst[e], s = src[e];
            atomicAdd(&deg2[d * NBIN + s / BINW], 1);
        }
    }
}

__global__ __launch_bounds__(256) void scan1_kernel(const int* __restrict__ deg2,
                                                    int* __restrict__ bsum) {
    int idx = blockIdx.x * 256 + threadIdx.x;
    int v = (idx < M2) ? deg2[idx] : 0;
#pragma unroll
    for (int off = 32; off > 0; off >>= 1) v += __shfl_down(v, off);
    __shared__ int ws[4];
    if ((threadIdx.x & 63) == 0) ws[threadIdx.x >> 6] = v;
    __syncthreads();
    if (threadIdx.x == 0) bsum[blockIdx.x] = ws[0] + ws[1] + ws[2] + ws[3];
}

// single block scans SB2 block-sums in chunks of 256 with a running carry
__global__ __launch_bounds__(256) void scan2_kernel(int* __restrict__ bsum) {
    __shared__ int s[256];
    __shared__ int carry_s;
    int t = threadIdx.x;
    if (t == 0) carry_s = 0;
    __syncthreads();
    const int NCH = (SB2 + 255) / 256;
    for (int c = 0; c < NCH; ++c) {
        int idx = c * 256 + t;
        int v = (idx < SB2) ? bsum[idx] : 0;
        s[t] = v;
        __syncthreads();
        for (int off = 1; off < 256; off <<= 1) {
            int u = (t >= off) ? s[t - off] : 0;
            __syncthreads();
            s[t] += u;
            __syncthreads();
        }
        int incl = s[t];
        int tot  = s[255];
        int base = carry_s;
        __syncthreads();   // all lanes read carry_s/s before t0 updates
        if (idx < SB2) bsum[idx] = base + incl - v;   // exclusive
        if (t == 0) carry_s = base + tot;
        __syncthreads();
    }
}

// local prefix + block offset -> base2 (and cursor2 = base2 for the scatter)
__global__ __launch_bounds__(256) void scan3_kernel(const int* __restrict__ deg2,
                                                    const int* __restrict__ bsum,
                                                    int* __restrict__ base2,
                                                    int* __restrict__ cursor2) {
    __shared__ int s[256];
    int t = threadIdx.x;
    int idx = blockIdx.x * 256 + t;
    int v = (idx < M2) ? deg2[idx] : 0;
    s[t] = v;
    __syncthreads();
    for (int off = 1; off < 256; off <<= 1) {
        int u = (t >= off) ? s[t - off] : 0;
        __syncthreads();
        s[t] += u;
        __syncthreads();
    }
    if (idx < M2) {
        int bv = bsum[blockIdx.x] + s[t] - v;
        base2[idx] = bv;
        cursor2[idx] = bv;
    }
    if (idx == 0) base2[M2] = N_EDGES;
}

// 16B record {h2(a0,a1), h2(a2,a3), h2(a4,a5), a6|src<<16} (src < 65536)
static __device__ __forceinline__ void write_rec(float* __restrict__ rec, int pos,
                                                 const float* __restrict__ ep, int s) {
    float4 v;
    *(__half2*)&v.x = __floats2half2_rn(ep[0], ep[1]);
    *(__half2*)&v.y = __floats2half2_rn(ep[2], ep[3]);
    *(__half2*)&v.z = __floats2half2_rn(ep[4], ep[5]);
    unsigned w = (unsigned)__half_as_ushort(__float2half_rn(ep[6])) |
                 ((unsigned)s << 16);
    v.w = __uint_as_float(w);
    *(float4*)(rec + (size_t)pos * 4) = v;
}

__global__ __launch_bounds__(256) void scatter_rec_kernel(
        const int* __restrict__ src,
        const int* __restrict__ dst,
        const float* __restrict__ ea,
        int* __restrict__ cursor2,
        float* __restrict__ rec) {
    const int T = gridDim.x * 256;
    const int t = blockIdx.x * 256 + threadIdx.x;
    const int e0 = t, e1 = t + T, e2 = t + 2 * T, e3 = t + 3 * T;
    const bool v3 = (e3 < N_EDGES);
    int d0 = dst[e0], d1 = dst[e1], d2 = dst[e2];
    int s0 = src[e0], s1 = src[e1], s2 = src[e2];
    int d3 = v3 ? dst[e3] : 0;
    int s3 = v3 ? src[e3] : 0;
    int p0 = atomicAdd(&cursor2[d0 * NBIN + s0 / BINW], 1);
    int p1 = atomicAdd(&cursor2[d1 * NBIN + s1 / BINW], 1);
    int p2 = atomicAdd(&cursor2[d2 * NBIN + s2 / BINW], 1);
    int p3 = v3 ? atomicAdd(&cursor2[d3 * NBIN + s3 / BINW], 1) : 0;
    write_rec(rec, p0, ea + (size_t)e0 * 7, s0);
    write_rec(rec, p1, ea + (size_t)e1 * 7, s1);
    write_rec(rec, p2, ea + (size_t)e2 * 7, s2);
    if (v3) write_rec(rec, p3, ea + (size_t)e3 * 7, s3);
}

// ---------------------------------------------------------------- layer 1 ---
// node n's edges span [base2[n*NBIN], base2[n*NBIN+NBIN]) — contiguous
__global__ __launch_bounds__(256) void layer1_kernel(
        const float* __restrict__ x,     // [N][2]
        const float* __restrict__ rec,   // [E][4] (16B records)
        const int* __restrict__ base2,   // [M2+1]
        const float* __restrict__ We1,   // [7][2]
        const float* __restrict__ be1,   // [2]
        const float* __restrict__ W1,    // [2][256]
        const float* __restrict__ b1,    // [256]
        unsigned* __restrict__ h8) {     // [N][64] dwords (fp8 x4)
    const int lane = threadIdx.x & 63;
    const int wid = threadIdx.x >> 6;
    const int n = blockIdx.x * 4 + wid;
    if (n >= N_NODES) return;
    float w00 = We1[0],  w01 = We1[1],  w10 = We1[2],  w11 = We1[3];
    float w20 = We1[4],  w21 = We1[5],  w30 = We1[6],  w31 = We1[7];
    float w40 = We1[8],  w41 = We1[9],  w50 = We1[10], w51 = We1[11];
    float w60 = We1[12], w61 = We1[13];
    float bb0 = be1[0], bb1 = be1[1];
    float m0 = 0.f, m1 = 0.f;
    const int s0 = base2[n * NBIN], s1 = base2[n * NBIN + NBIN];
    for (int pos = s0 + lane; pos < s1; pos += 64) {
        float4 a = *(const float4*)(rec + (size_t)pos * 4);
        __half2 hx = *(__half2*)&a.x;
        __half2 hy = *(__half2*)&a.y;
        __half2 hz = *(__half2*)&a.z;
        __half2 hw = *(__half2*)&a.w;
        unsigned uw = __float_as_uint(a.w);
        int s = (int)(uw >> 16);
        float a0 = __low2float(hx),  a1 = __high2float(hx);
        float a2 = __low2float(hy),  a3 = __high2float(hy);
        float a4 = __low2float(hz),  a5 = __high2float(hz);
        float a6 = __low2float(hw);
        float t0 = bb0, t1 = bb1;
        t0 = fmaf(a0, w00, t0); t1 = fmaf(a0, w01, t1);
        t0 = fmaf(a1, w10, t0); t1 = fmaf(a1, w11, t1);
        t0 = fmaf(a2, w20, t0); t1 = fmaf(a2, w21, t1);
        t0 = fmaf(a3, w30, t0); t1 = fmaf(a3, w31, t1);
        t0 = fmaf(a4, w40, t0); t1 = fmaf(a4, w41, t1);
        t0 = fmaf(a5, w50, t0); t1 = fmaf(a5, w51, t1);
        t0 = fmaf(a6, w60, t0); t1 = fmaf(a6, w61, t1);
        float2 xv = *(const float2*)&x[(size_t)s * 2];
        m0 += fmaxf(t0 + xv.x, 0.f);
        m1 += fmaxf(t1 + xv.y, 0.f);
    }
#pragma unroll
    for (int off = 32; off > 0; off >>= 1) {
        m0 += __shfl_down(m0, off);
        m1 += __shfl_down(m1, off);
    }
    m0 = __shfl(m0, 0);
    m1 = __shfl(m1, 0);
    const float t0 = x[n * 2 + 0] + m0;
    const float t1 = x[n * 2 + 1] + m1;
    const int c = lane * 4;
    float4 wa = *(const float4*)&W1[c];
    float4 wb = *(const float4*)&W1[256 + c];
    float4 bv = *(const float4*)&b1[c];
    float4 r;
    r.x = fmaxf(fmaf(t0, wa.x, fmaf(t1, wb.x, bv.x)), 0.f);
    r.y = fmaxf(fmaf(t0, wa.y, fmaf(t1, wb.y, bv.y)), 0.f);
    r.z = fmaxf(fmaf(t0, wa.z, fmaf(t1, wb.z, bv.z)), 0.f);
    r.w = fmaxf(fmaf(t0, wa.w, fmaf(t1, wb.w, bv.w)), 0.f);
    h8[(size_t)n * 64 + lane] = pack4_fp8(r.x, r.y, r.z, r.w);
}

// ------------------------------------------------------------ layers 2..3 ---
// Phase-synchronized src-binned aggregation. 391 blocks × 128 nodes, ALL
// co-resident (64KB LDS -> 2 blocks/CU). Outer loop over 8 src bins: the
// whole GPU gathers from one 1.6MB h8 slice at a time -> L2 hits; only
// compulsory fills (12.8MB x 8 XCD) miss. Accumulators live in LDS; each
// wave owns 32 nodes (disjoint LDS regions, no barriers needed).
#define EDGEH4(RA, HU, VLD)                                            \
    do {                                                               \
        unsigned _ux = __float_as_uint(RA.x);                          \
        unsigned _uy = __float_as_uint(RA.y);                          \
        unsigned _uz = __float_as_uint(RA.z);                          \
        unsigned _uw = __float_as_uint(RA.w);                          \
        unsigned _m0 = bb01u, _m1 = bb23u;                             \
        PKFMA_LO(_m0, _ux, w0au); PKFMA_LO(_m1, _ux, w0bu);            \
        PKFMA_HI(_m0, _ux, w1au); PKFMA_HI(_m1, _ux, w1bu);            \
        PKFMA_LO(_m0, _uy, w2au); PKFMA_LO(_m1, _uy, w2bu);            \
        PKFMA_HI(_m0, _uy, w3au); PKFMA_HI(_m1, _uy, w3bu);            \
        PKFMA_LO(_m0, _uz, w4au); PKFMA_LO(_m1, _uz, w4bu);            \
        PKFMA_HI(_m0, _uz, w5au); PKFMA_HI(_m1, _uz, w5bu);            \
        PKFMA_LO(_m0, _uw, w6au); PKFMA_LO(_m1, _uw, w6bu);            \
        v2f _hf0 = __builtin_amdgcn_cvt_pk_f32_fp8((int)(HU), false);  \
        v2f _hf1 = __builtin_amdgcn_cvt_pk_f32_fp8((int)(HU), true);   \
        __half2 _h0 = __float22half2_rn(make_float2(_hf0.x, _hf0.y));  \
        __half2 _h1 = __float22half2_rn(make_float2(_hf1.x, _hf1.y));  \
        __half2 _m0h = u2h(_m0), _m1h = u2h(_m1);                      \
        _m0h = pk_max2(__hadd2(_m0h, _h0), z2);                        \
        _m1h = pk_max2(__hadd2(_m1h, _h1), z2);                        \
        unsigned _r0 = h2bits(_m0h), _r1 = h2bits(_m1h);               \
        _r0 = (VLD) ? _r0 : 0u;   /* +0 add is exact (relu >= 0) */    \
        _r1 = (VLD) ? _r1 : 0u;                                        \
        acc0 = __hadd2(acc0, u2h(_r0));                                \
        acc1 = __hadd2(acc1, u2h(_r1));                                \
    } while (0)

__global__ __launch_bounds__(256) void aggr2_kernel(
        const unsigned* __restrict__ h8,  // [N][64] dwords (fp8 x4)
        const float* __restrict__ rec,    // [E][4] (dst, src-bin)-sorted
        const int* __restrict__ base2,    // [M2+1]
        const float* __restrict__ We2,    // [7][256] fp32
        const float* __restrict__ be2,    // [256] fp32
        __half* __restrict__ accum) {     // [N][256] fp16 out
    __shared__ uint2 accs[V2_NODES * 64];   // 64KB: 128 nodes x 256ch fp16
    const int lane = threadIdx.x & 63;
    const int w = threadIdx.x >> 6;
    const int n0 = blockIdx.x * V2_NODES + w * 32;   // wave's first node
    const int c4 = lane * 4;
    const unsigned w0au = h2u(We2[0 * HID + c4], We2[0 * HID + c4 + 1]);
    const unsigned w0bu = h2u(We2[0 * HID + c4 + 2], We2[0 * HID + c4 + 3]);
    const unsigned w1au = h2u(We2[1 * HID + c4], We2[1 * HID + c4 + 1]);
    const unsigned w1bu = h2u(We2[1 * HID + c4 + 2], We2[1 * HID + c4 + 3]);
    const unsigned w2au = h2u(We2[2 * HID + c4], We2[2 * HID + c4 + 1]);
    const unsigned w2bu = h2u(We2[2 * HID + c4 + 2], We2[2 * HID + c4 + 3]);
    const unsigned w3au = h2u(We2[3 * HID + c4], We2[3 * HID + c4 + 1]);
    const unsigned w3bu = h2u(We2[3 * HID + c4 + 2], We2[3 * HID + c4 + 3]);
    const unsigned w4au = h2u(We2[4 * HID + c4], We2[4 * HID + c4 + 1]);
    const unsigned w4bu = h2u(We2[4 * HID + c4 + 2], We2[4 * HID + c4 + 3]);
    const unsigned w5au = h2u(We2[5 * HID + c4], We2[5 * HID + c4 + 1]);
    const unsigned w5bu = h2u(We2[5 * HID + c4 + 2], We2[5 * HID + c4 + 3]);
    const unsigned w6au = h2u(We2[6 * HID + c4], We2[6 * HID + c4 + 1]);
    const unsigned w6bu = h2u(We2[6 * HID + c4 + 2], We2[6 * HID + c4 + 3]);
    const unsigned bb01u = h2u(be2[c4], be2[c4 + 1]);
    const unsigned bb23u = h2u(be2[c4 + 2], be2[c4 + 3]);
    const __half2 z2 = __float2half2_rn(0.f);

    uint2* ap = accs + (size_t)(w * 32) * 64 + lane;   // + j*64 per node
    for (int j = 0; j < 32; ++j) ap[j * 64] = make_uint2(0u, 0u);

    const f32x4* rp = (const f32x4*)rec;
    for (int b = 0; b < NBIN; ++b) {
        for (int j = 0; j < 32; ++j) {
            int n = n0 + j;
            if (n >= N_NODES) break;
            int s0 = __builtin_amdgcn_readfirstlane(base2[n * NBIN + b]);
            int s1 = __builtin_amdgcn_readfirstlane(base2[n * NBIN + b + 1]);
            if (s1 <= s0) continue;
            __half2 acc0 = z2, acc1 = z2;
            int last = s1 - 1;
            for (int e = s0; e < s1; e += 4) {
                int i1 = min(e + 1, last), i2 = min(e + 2, last), i3 = min(e + 3, last);
                bool v1 = (e + 1 <= last), v2 = (e + 2 <= last), v3 = (e + 3 <= last);
                f32x4 a0 = rp[e], a1 = rp[i1], a2 = rp[i2], a3 = rp[i3];
                unsigned h0 = h8[(size_t)(__float_as_uint(a0.w) >> 16) * 64 + lane];
                unsigned h1 = h8[(size_t)(__float_as_uint(a1.w) >> 16) * 64 + lane];
                unsigned h2 = h8[(size_t)(__float_as_uint(a2.w) >> 16) * 64 + lane];
                unsigned h3 = h8[(size_t)(__float_as_uint(a3.w) >> 16) * 64 + lane];
                EDGEH4(a0, h0, true);
                EDGEH4(a1, h1, v1);
                EDGEH4(a2, h2, v2);
                EDGEH4(a3, h3, v3);
            }
            uint2 p = ap[j * 64];
            p.x = h2bits(__hadd2(u2h(p.x), acc0));
            p.y = h2bits(__hadd2(u2h(p.y), acc1));
            ap[j * 64] = p;
        }
    }
    // epilogue: self term + store
    for (int j = 0; j < 32; ++j) {
        int n = n0 + j;
        if (n >= N_NODES) break;
        uint2 p = ap[j * 64];
        __half2 acc0 = u2h(p.x), acc1 = u2h(p.y);
        unsigned hv = h8[(size_t)n * 64 + lane];
        v2f f0 = __builtin_amdgcn_cvt_pk_f32_fp8((int)hv, false);
        v2f f1 = __builtin_amdgcn_cvt_pk_f32_fp8((int)hv, true);
        acc0 = __hadd2(acc0, __float22half2_rn(make_float2(f0.x, f0.y)));
        acc1 = __hadd2(acc1, __float22half2_rn(make_float2(f1.x, f1.y)));
        float2 of;
        *(__half2*)&of.x = acc0;
        *(__half2*)&of.y = acc1;
        *(float2*)&accum[(size_t)n * HID + c4] = of;
    }
}

// ------------------------------------------------- W2 -> fp16 B-frag swizzle ---
__global__ __launch_bounds__(256) void w2_swizzle_kernel(const float* __restrict__ W,
                                                         __half* __restrict__ W2s) {
    int t = blockIdx.x * 256 + threadIdx.x;   // 16*8*64 = 8192
    if (t >= 16 * 8 * 64) return;
    int lane = t & 63;
    int kc = (t >> 6) & 7;
    int ct = t >> 9;
    int k0 = kc * 32 + (lane >> 4) * 8;
    int col = ct * 16 + (lane & 15);
#pragma unroll
    for (int j = 0; j < 8; ++j)
        W2s[(size_t)t * 8 + j] = __float2half(W[(size_t)(k0 + j) * HID + col]);
}

// ---------------------------------------------------------------- node MLP ---
template <bool FUSE_END>
__global__ __launch_bounds__(256) void node2_mfma_kernel(
        const __half* __restrict__ A,     // [N][256] fp16 (accum)
        const __half* __restrict__ W2s,   // swizzled B-frags
        const float* __restrict__ b,      // [256]
        unsigned char* __restrict__ h8,   // [N][256] fp8 out (!FUSE_END)
        const float* __restrict__ Wend,   // [256] (FUSE_END)
        const float* __restrict__ bend,   // [1]   (FUSE_END)
        float* __restrict__ out) {        // [N] (FUSE_END)
    const int lane = threadIdx.x & 63;
    const int wv = threadIdx.x >> 6;
    const int n_base = blockIdx.x * 64 + wv * 16;
    if (n_base >= N_NODES) return;
    const int quad = lane >> 4;
    const int mrow = lane & 15;
    f16x8 af[8];
    const __half* ap = A + (size_t)(n_base + mrow) * HID + quad * 8;
#pragma unroll
    for (int kc = 0; kc < 8; ++kc)
        af[kc] = *(const f16x8*)(ap + kc * 32);
    float p0 = 0.f, p1 = 0.f, p2 = 0.f, p3 = 0.f;
#pragma unroll
    for (int ct = 0; ct < 16; ++ct) {
        f32x4 c = {0.f, 0.f, 0.f, 0.f};
        const f16x8* bp = (const f16x8*)W2s + (size_t)(ct * 8) * 64 + lane;
#pragma unroll
        for (int kc = 0; kc < 8; ++kc)
            c = __builtin_amdgcn_mfma_f32_16x16x32_f16(af[kc], bp[(size_t)kc * 64],
                                                       c, 0, 0, 0);
        const int col = ct * 16 + mrow;
        const float bias = b[col];
        if (!FUSE_END) {
#pragma unroll
            for (int r = 0; r < 4; ++r) {
                int n = n_base + quad * 4 + r;
                float v = fmaxf(c[r] + bias, 0.f);
                int pk = __builtin_amdgcn_cvt_pk_fp8_f32(v, v, 0, false);
                if (n < N_NODES)
                    h8[(size_t)n * HID + col] = (unsigned char)(pk & 0xff);
            }
        } else {
            const float we = Wend[col];
            p0 = fmaf(fmaxf(c[0] + bias, 0.f), we, p0);
            p1 = fmaf(fmaxf(c[1] + bias, 0.f), we, p1);
            p2 = fmaf(fmaxf(c[2] + bias, 0.f), we, p2);
            p3 = fmaf(fmaxf(c[3] + bias, 0.f), we, p3);
        }
    }
    if (FUSE_END) {
#pragma unroll
        for (int mask = 1; mask < 16; mask <<= 1) {
            p0 += __shfl_xor(p0, mask);
            p1 += __shfl_xor(p1, mask);
            p2 += __shfl_xor(p2, mask);
            p3 += __shfl_xor(p3, mask);
        }
        if (mrow == 0) {
            const float bd = bend[0];
            int n = n_base + quad * 4;
            if (n + 0 < N_NODES) out[n + 0] = 1.f / (1.f + expf(-(p0 + bd)));
            if (n + 1 < N_NODES) out[n + 1] = 1.f / (1.f + expf(-(p1 + bd)));
            if (n + 2 < N_NODES) out[n + 2] = 1.f / (1.f + expf(-(p2 + bd)));
            if (n + 3 < N_NODES) out[n + 3] = 1.f / (1.f + expf(-(p3 + bd)));
        }
    }
}

// ------------------------------------------------------------------ launch ---
extern "C" void kernel_launch(void* const* d_in, const int* in_sizes, int n_in,
                              void* d_out, int out_size, void* d_ws, size_t ws_size,
                              hipStream_t stream) {
    const float* x    = (const float*)d_in[0];
    const int*   ei   = (const int*)d_in[1];
    const float* ea   = (const float*)d_in[2];
    const float* We1  = (const float*)d_in[3];
    const float* be1  = (const float*)d_in[4];
    const float* W1   = (const float*)d_in[5];
    const float* b1   = (const float*)d_in[6];
    const float* We2  = (const float*)d_in[7];
    const float* be2  = (const float*)d_in[8];
    const float* W2   = (const float*)d_in[9];
    const float* b2   = (const float*)d_in[10];
    const float* Wend = (const float*)d_in[11];
    const float* bend = (const float*)d_in[12];
    float* out = (float*)d_out;

    const int* src = ei;
    const int* dst = ei + N_EDGES;

    const size_t HN = (size_t)N_NODES * HID;           // 12.8M elements
    __half*   Bh   = (__half*)d_ws;                    // [N][256] fp16 accum
    unsigned* Ah   = (unsigned*)(Bh + HN);             // [N][64] fp8x4 h
    float*    rec  = (float*)(Ah + (size_t)N_NODES * 64); // [E][4] 16B records
    __half*   W2s  = (__half*)(rec + (size_t)N_EDGES * 4);
    int*   deg2    = (int*)(W2s + 16 * 8 * 64 * 8);    // [M2]
    int*   cursor2 = deg2 + M2;                        // [M2]
    int*   base2   = cursor2 + M2;                     // [M2+1]
    int*   bsum    = base2 + M2 + 1;                   // [SB2]
    // total ≈ 69 MB

    const int E4_B = (N_EDGES + 4 * 256 - 1) / (4 * 256);   // 1563

    // ---- binned CSR build + record sort (shared by all 3 layers)
    hipMemsetAsync(deg2, 0, (size_t)M2 * sizeof(int), stream);
    hist_kernel<<<E4_B, 256, 0, stream>>>(src, dst, deg2);
    scan1_kernel<<<SB2, 256, 0, stream>>>(deg2, bsum);
    scan2_kernel<<<1, 256, 0, stream>>>(bsum);
    scan3_kernel<<<SB2, 256, 0, stream>>>(deg2, bsum, base2, cursor2);
    scatter_rec_kernel<<<E4_B, 256, 0, stream>>>(src, dst, ea, cursor2, rec);
    w2_swizzle_kernel<<<32, 256, 0, stream>>>(W2, W2s);

    // ---- layer 1 (fused gather + MLP) -> Ah (fp8)
    layer1_kernel<<<(N_NODES + 3) / 4, 256, 0, stream>>>(x, rec, base2, We1, be1,
                                                         W1, b1, Ah);

    const int N2_B = (N_NODES + 63) / 64;
    // ---- layer 2
    aggr2_kernel<<<V2_GRID, 256, 0, stream>>>(Ah, rec, base2, We2, be2, Bh);
    node2_mfma_kernel<false><<<N2_B, 256, 0, stream>>>(Bh, W2s, b2,
                                                       (unsigned char*)Ah,
                                                       nullptr, nullptr, nullptr);
    // ---- layer 3 + fused head
    aggr2_kernel<<<V2_GRID, 256, 0, stream>>>(Ah, rec, base2, We2, be2, Bh);
    node2_mfma_kernel<true><<<N2_B, 256, 0, stream>>>(Bh, W2s, b2, nullptr,
                                                      Wend, bend, out);
}

// Round 7
// 858.858 us; speedup vs baseline: 1.3114x; 1.3114x over previous
//
#include <hip/hip_runtime.h>
#include <hip/hip_fp16.h>
#include <math.h>

#define N_NODES 50000
#define N_EDGES 1600000
#define HID 256
#define NBIN 8                 // src-range bins (slice = 6250 nodes = 1.6MB of h8)
#define BINW 6250              // N_NODES / NBIN
#define M2 (N_NODES * NBIN)    // 400000 (dst,bin) counters
#define SB2 ((M2 + 255) / 256) // 1563 scan blocks
#define V2_NODES 64            // nodes per aggr2 block (32KB LDS accum)
#define V2_GRID ((N_NODES + V2_NODES - 1) / V2_NODES)  // 782 — all co-resident
// eps = 0

typedef _Float16 f16x8 __attribute__((ext_vector_type(8)));
typedef float f32x4 __attribute__((ext_vector_type(4)));
typedef float v2f __attribute__((ext_vector_type(2)));

// ROCm 7.2 has no __hmax2 — emit v_pk_max_f16 directly.
static __device__ __forceinline__ __half2 pk_max2(__half2 a, __half2 b) {
    unsigned au = *reinterpret_cast<unsigned*>(&a);
    unsigned bu = *reinterpret_cast<unsigned*>(&b);
    unsigned r;
    asm("v_pk_max_f16 %0, %1, %2" : "=v"(r) : "v"(au), "v"(bu));
    return *reinterpret_cast<__half2*>(&r);
}

// half2 held as a raw dword (for VOP3P inline asm operands)
static __device__ __forceinline__ unsigned h2u(float lo, float hi) {
    __half2 t = __floats2half2_rn(lo, hi);
    return *reinterpret_cast<unsigned*>(&t);
}

static __device__ __forceinline__ __half2 u2h(unsigned u) {
    return *reinterpret_cast<__half2*>(&u);
}
static __device__ __forceinline__ unsigned h2bits(__half2 h) {
    return *reinterpret_cast<unsigned*>(&h);
}

// packed fp16 FMA with the LOW half of ATTR broadcast to both result halves
#define PKFMA_LO(ACC, ATTR, W)                                           \
    asm("v_pk_fma_f16 %0, %1, %2, %0 op_sel:[0,0,0] op_sel_hi:[0,1,1]"   \
        : "+v"(ACC) : "v"(ATTR), "v"(W))
// packed fp16 FMA with the HIGH half of ATTR broadcast to both result halves
#define PKFMA_HI(ACC, ATTR, W)                                           \
    asm("v_pk_fma_f16 %0, %1, %2, %0 op_sel:[1,0,0] op_sel_hi:[1,1,1]"   \
        : "+v"(ACC) : "v"(ATTR), "v"(W))

// 4 floats -> 4 fp8 (e4m3) packed in one dword
static __device__ __forceinline__ unsigned pack4_fp8(float a, float b, float c, float d) {
    int v = __builtin_amdgcn_cvt_pk_fp8_f32(a, b, 0, false);
    v = __builtin_amdgcn_cvt_pk_fp8_f32(c, d, v, true);
    return (unsigned)v;
}

// ---------------------------------------------------------------- CSR build ---
// counters indexed dst*NBIN + src/BINW -> records sorted (dst, src-bin)
__global__ __launch_bounds__(256) void hist_kernel(const int* __restrict__ src,
                                                   const int* __restrict__ dst,
                                                   int* __restrict__ deg2) {
    const int T = gridDim.x * 256;
    const int t = blockIdx.x * 256 + threadIdx.x;
#pragma unroll
    for (int i = 0; i < 4; ++i) {
        int e = t + i * T;
        if (e < N_EDGES) {
            int d = dst[e], s = src[e];
            atomicAdd(&deg2[d * NBIN + s / BINW], 1);
        }
    }
}

__global__ __launch_bounds__(256) void scan1_kernel(const int* __restrict__ deg2,
                                                    int* __restrict__ bsum) {
    int idx = blockIdx.x * 256 + threadIdx.x;
    int v = (idx < M2) ? deg2[idx] : 0;
#pragma unroll
    for (int off = 32; off > 0; off >>= 1) v += __shfl_down(v, off);
    __shared__ int ws[4];
    if ((threadIdx.x & 63) == 0) ws[threadIdx.x >> 6] = v;
    __syncthreads();
    if (threadIdx.x == 0) bsum[blockIdx.x] = ws[0] + ws[1] + ws[2] + ws[3];
}

// single block scans SB2 block-sums in chunks of 256 with a running carry
__global__ __launch_bounds__(256) void scan2_kernel(int* __restrict__ bsum) {
    __shared__ int s[256];
    __shared__ int carry_s;
    int t = threadIdx.x;
    if (t == 0) carry_s = 0;
    __syncthreads();
    const int NCH = (SB2 + 255) / 256;
    for (int c = 0; c < NCH; ++c) {
        int idx = c * 256 + t;
        int v = (idx < SB2) ? bsum[idx] : 0;
        s[t] = v;
        __syncthreads();
        for (int off = 1; off < 256; off <<= 1) {
            int u = (t >= off) ? s[t - off] : 0;
            __syncthreads();
            s[t] += u;
            __syncthreads();
        }
        int incl = s[t];
        int tot  = s[255];
        int base = carry_s;
        __syncthreads();   // all lanes read carry_s/s before t0 updates
        if (idx < SB2) bsum[idx] = base + incl - v;   // exclusive
        if (t == 0) carry_s = base + tot;
        __syncthreads();
    }
}

// local prefix + block offset -> base2 (and cursor2 = base2 for the scatter)
__global__ __launch_bounds__(256) void scan3_kernel(const int* __restrict__ deg2,
                                                    const int* __restrict__ bsum,
                                                    int* __restrict__ base2,
                                                    int* __restrict__ cursor2) {
    __shared__ int s[256];
    int t = threadIdx.x;
    int idx = blockIdx.x * 256 + t;
    int v = (idx < M2) ? deg2[idx] : 0;
    s[t] = v;
    __syncthreads();
    for (int off = 1; off < 256; off <<= 1) {
        int u = (t >= off) ? s[t - off] : 0;
        __syncthreads();
        s[t] += u;
        __syncthreads();
    }
    if (idx < M2) {
        int bv = bsum[blockIdx.x] + s[t] - v;
        base2[idx] = bv;
        cursor2[idx] = bv;
    }
    if (idx == 0) base2[M2] = N_EDGES;
}

// 16B record {h2(a0,a1), h2(a2,a3), h2(a4,a5), a6|src<<16} (src < 65536)
static __device__ __forceinline__ void write_rec(float* __restrict__ rec, int pos,
                                                 const float* __restrict__ ep, int s) {
    float4 v;
    *(__half2*)&v.x = __floats2half2_rn(ep[0], ep[1]);
    *(__half2*)&v.y = __floats2half2_rn(ep[2], ep[3]);
    *(__half2*)&v.z = __floats2half2_rn(ep[4], ep[5]);
    unsigned w = (unsigned)__half_as_ushort(__float2half_rn(ep[6])) |
                 ((unsigned)s << 16);
    v.w = __uint_as_float(w);
    *(float4*)(rec + (size_t)pos * 4) = v;
}

__global__ __launch_bounds__(256) void scatter_rec_kernel(
        const int* __restrict__ src,
        const int* __restrict__ dst,
        const float* __restrict__ ea,
        int* __restrict__ cursor2,
        float* __restrict__ rec) {
    const int T = gridDim.x * 256;
    const int t = blockIdx.x * 256 + threadIdx.x;
    const int e0 = t, e1 = t + T, e2 = t + 2 * T, e3 = t + 3 * T;
    const bool v3 = (e3 < N_EDGES);
    int d0 = dst[e0], d1 = dst[e1], d2 = dst[e2];
    int s0 = src[e0], s1 = src[e1], s2 = src[e2];
    int d3 = v3 ? dst[e3] : 0;
    int s3 = v3 ? src[e3] : 0;
    int p0 = atomicAdd(&cursor2[d0 * NBIN + s0 / BINW], 1);
    int p1 = atomicAdd(&cursor2[d1 * NBIN + s1 / BINW], 1);
    int p2 = atomicAdd(&cursor2[d2 * NBIN + s2 / BINW], 1);
    int p3 = v3 ? atomicAdd(&cursor2[d3 * NBIN + s3 / BINW], 1) : 0;
    write_rec(rec, p0, ea + (size_t)e0 * 7, s0);
    write_rec(rec, p1, ea + (size_t)e1 * 7, s1);
    write_rec(rec, p2, ea + (size_t)e2 * 7, s2);
    if (v3) write_rec(rec, p3, ea + (size_t)e3 * 7, s3);
}

// ---------------------------------------------------------------- layer 1 ---
// node n's edges span [base2[n*NBIN], base2[n*NBIN+NBIN]) — contiguous
__global__ __launch_bounds__(256) void layer1_kernel(
        const float* __restrict__ x,     // [N][2]
        const float* __restrict__ rec,   // [E][4] (16B records)
        const int* __restrict__ base2,   // [M2+1]
        const float* __restrict__ We1,   // [7][2]
        const float* __restrict__ be1,   // [2]
        const float* __restrict__ W1,    // [2][256]
        const float* __restrict__ b1,    // [256]
        unsigned* __restrict__ h8) {     // [N][64] dwords (fp8 x4)
    const int lane = threadIdx.x & 63;
    const int wid = threadIdx.x >> 6;
    const int n = blockIdx.x * 4 + wid;
    if (n >= N_NODES) return;
    float w00 = We1[0],  w01 = We1[1],  w10 = We1[2],  w11 = We1[3];
    float w20 = We1[4],  w21 = We1[5],  w30 = We1[6],  w31 = We1[7];
    float w40 = We1[8],  w41 = We1[9],  w50 = We1[10], w51 = We1[11];
    float w60 = We1[12], w61 = We1[13];
    float bb0 = be1[0], bb1 = be1[1];
    float m0 = 0.f, m1 = 0.f;
    const int s0 = base2[n * NBIN], s1 = base2[n * NBIN + NBIN];
    for (int pos = s0 + lane; pos < s1; pos += 64) {
        float4 a = *(const float4*)(rec + (size_t)pos * 4);
        __half2 hx = *(__half2*)&a.x;
        __half2 hy = *(__half2*)&a.y;
        __half2 hz = *(__half2*)&a.z;
        __half2 hw = *(__half2*)&a.w;
        unsigned uw = __float_as_uint(a.w);
        int s = (int)(uw >> 16);
        float a0 = __low2float(hx),  a1 = __high2float(hx);
        float a2 = __low2float(hy),  a3 = __high2float(hy);
        float a4 = __low2float(hz),  a5 = __high2float(hz);
        float a6 = __low2float(hw);
        float t0 = bb0, t1 = bb1;
        t0 = fmaf(a0, w00, t0); t1 = fmaf(a0, w01, t1);
        t0 = fmaf(a1, w10, t0); t1 = fmaf(a1, w11, t1);
        t0 = fmaf(a2, w20, t0); t1 = fmaf(a2, w21, t1);
        t0 = fmaf(a3, w30, t0); t1 = fmaf(a3, w31, t1);
        t0 = fmaf(a4, w40, t0); t1 = fmaf(a4, w41, t1);
        t0 = fmaf(a5, w50, t0); t1 = fmaf(a5, w51, t1);
        t0 = fmaf(a6, w60, t0); t1 = fmaf(a6, w61, t1);
        float2 xv = *(const float2*)&x[(size_t)s * 2];
        m0 += fmaxf(t0 + xv.x, 0.f);
        m1 += fmaxf(t1 + xv.y, 0.f);
    }
#pragma unroll
    for (int off = 32; off > 0; off >>= 1) {
        m0 += __shfl_down(m0, off);
        m1 += __shfl_down(m1, off);
    }
    m0 = __shfl(m0, 0);
    m1 = __shfl(m1, 0);
    const float t0 = x[n * 2 + 0] + m0;
    const float t1 = x[n * 2 + 1] + m1;
    const int c = lane * 4;
    float4 wa = *(const float4*)&W1[c];
    float4 wb = *(const float4*)&W1[256 + c];
    float4 bv = *(const float4*)&b1[c];
    float4 r;
    r.x = fmaxf(fmaf(t0, wa.x, fmaf(t1, wb.x, bv.x)), 0.f);
    r.y = fmaxf(fmaf(t0, wa.y, fmaf(t1, wb.y, bv.y)), 0.f);
    r.z = fmaxf(fmaf(t0, wa.z, fmaf(t1, wb.z, bv.z)), 0.f);
    r.w = fmaxf(fmaf(t0, wa.w, fmaf(t1, wb.w, bv.w)), 0.f);
    h8[(size_t)n * 64 + lane] = pack4_fp8(r.x, r.y, r.z, r.w);
}

// ------------------------------------------------------------ layers 2..3 ---
// Phase-synchronized src-binned aggregation, latency-tolerant schedule:
// 782 blocks x 64 nodes (32KB LDS -> 5 blocks/CU, all co-resident). Outer
// loop over 8 src bins (whole GPU on one 1.6MB h8 slice -> L2 hits). Per
// (wave,bin): bounds for the wave's 16 nodes fetched by ONE per-lane vector
// load + v_readlane (no serial s_loads); node segments consumed in a
// ping-pong pair pipeline (8 rec + 8 h loads in flight).
#define EDGEH4(RA, HU, VLD)                                            \
    do {                                                               \
        unsigned _ux = __float_as_uint(RA.x);                          \
        unsigned _uy = __float_as_uint(RA.y);                          \
        unsigned _uz = __float_as_uint(RA.z);                          \
        unsigned _uw = __float_as_uint(RA.w);                          \
        unsigned _m0 = bb01u, _m1 = bb23u;                             \
        PKFMA_LO(_m0, _ux, w0au); PKFMA_LO(_m1, _ux, w0bu);            \
        PKFMA_HI(_m0, _ux, w1au); PKFMA_HI(_m1, _ux, w1bu);            \
        PKFMA_LO(_m0, _uy, w2au); PKFMA_LO(_m1, _uy, w2bu);            \
        PKFMA_HI(_m0, _uy, w3au); PKFMA_HI(_m1, _uy, w3bu);            \
        PKFMA_LO(_m0, _uz, w4au); PKFMA_LO(_m1, _uz, w4bu);            \
        PKFMA_HI(_m0, _uz, w5au); PKFMA_HI(_m1, _uz, w5bu);            \
        PKFMA_LO(_m0, _uw, w6au); PKFMA_LO(_m1, _uw, w6bu);            \
        v2f _hf0 = __builtin_amdgcn_cvt_pk_f32_fp8((int)(HU), false);  \
        v2f _hf1 = __builtin_amdgcn_cvt_pk_f32_fp8((int)(HU), true);   \
        __half2 _h0 = __float22half2_rn(make_float2(_hf0.x, _hf0.y));  \
        __half2 _h1 = __float22half2_rn(make_float2(_hf1.x, _hf1.y));  \
        __half2 _m0h = u2h(_m0), _m1h = u2h(_m1);                      \
        _m0h = pk_max2(__hadd2(_m0h, _h0), z2);                        \
        _m1h = pk_max2(__hadd2(_m1h, _h1), z2);                        \
        unsigned _r0 = h2bits(_m0h), _r1 = h2bits(_m1h);               \
        _r0 = (VLD) ? _r0 : 0u;   /* +0 add is exact (relu >= 0) */    \
        _r1 = (VLD) ? _r1 : 0u;                                        \
        acc0 = __hadd2(acc0, u2h(_r0));                                \
        acc1 = __hadd2(acc1, u2h(_r1));                                \
    } while (0)

// issue first-chunk loads for a segment (clamped; OOB-by-16B reads stay in ws)
#define SEGLOAD(A0, A1, A2, A3, H0, H1, H2, H3, S0, S1)                \
    do {                                                               \
        int _last = (S1) - 1;                                          \
        int _i1 = min((S0) + 1, _last);                                \
        int _i2 = min((S0) + 2, _last);                                \
        int _i3 = min((S0) + 3, _last);                                \
        A0 = rp[(S0)]; A1 = rp[_i1]; A2 = rp[_i2]; A3 = rp[_i3];       \
        H0 = h8[(size_t)(__float_as_uint(A0.w) >> 16) * 64 + lane];    \
        H1 = h8[(size_t)(__float_as_uint(A1.w) >> 16) * 64 + lane];    \
        H2 = h8[(size_t)(__float_as_uint(A2.w) >> 16) * 64 + lane];    \
        H3 = h8[(size_t)(__float_as_uint(A3.w) >> 16) * 64 + lane];    \
    } while (0)

// consume a segment: first chunk from regs, tail chunks loaded inline
#define CONSUME(A0, A1, A2, A3, H0, H1, H2, H3, S0, S1, J)             \
    do {                                                               \
        bool _v0 = (S0) < (S1),     _v1 = (S0) + 1 < (S1);             \
        bool _v2 = (S0) + 2 < (S1), _v3 = (S0) + 3 < (S1);             \
        __half2 acc0 = z2, acc1 = z2;                                  \
        EDGEH4(A0, H0, _v0); EDGEH4(A1, H1, _v1);                      \
        EDGEH4(A2, H2, _v2); EDGEH4(A3, H3, _v3);                      \
        int _l = (S1) - 1;                                             \
        for (int _e = (S0) + 4; _e < (S1); _e += 4) {                  \
            int _j1 = min(_e + 1, _l), _j2 = min(_e + 2, _l),          \
                _j3 = min(_e + 3, _l);                                 \
            bool _w1 = _e + 1 <= _l, _w2 = _e + 2 <= _l,               \
                 _w3 = _e + 3 <= _l;                                   \
            f32x4 _b0 = rp[_e], _b1 = rp[_j1], _b2 = rp[_j2],          \
                  _b3 = rp[_j3];                                       \
            unsigned _g0 = h8[(size_t)(__float_as_uint(_b0.w) >> 16) * 64 + lane]; \
            unsigned _g1 = h8[(size_t)(__float_as_uint(_b1.w) >> 16) * 64 + lane]; \
            unsigned _g2 = h8[(size_t)(__float_as_uint(_b2.w) >> 16) * 64 + lane]; \
            unsigned _g3 = h8[(size_t)(__float_as_uint(_b3.w) >> 16) * 64 + lane]; \
            EDGEH4(_b0, _g0, true); EDGEH4(_b1, _g1, _w1);             \
            EDGEH4(_b2, _g2, _w2);  EDGEH4(_b3, _g3, _w3);             \
        }                                                              \
        if (_v0) {                                                     \
            uint2 _p = ap[(J) * 64];                                   \
            _p.x = h2bits(__hadd2(u2h(_p.x), acc0));                   \
            _p.y = h2bits(__hadd2(u2h(_p.y), acc1));                   \
            ap[(J) * 64] = _p;                                         \
        }                                                              \
    } while (0)

__global__ __launch_bounds__(256) void aggr2_kernel(
        const unsigned* __restrict__ h8,  // [N][64] dwords (fp8 x4)
        const float* __restrict__ rec,    // [E][4] (dst, src-bin)-sorted
        const int* __restrict__ base2,    // [M2+1]
        const float* __restrict__ We2,    // [7][256] fp32
        const float* __restrict__ be2,    // [256] fp32
        __half* __restrict__ accum) {     // [N][256] fp16 out
    __shared__ uint2 accs[V2_NODES * 64];   // 32KB: 64 nodes x 256ch fp16
    const int lane = threadIdx.x & 63;
    const int w = threadIdx.x >> 6;
    const int n0 = blockIdx.x * V2_NODES + w * 16;   // wave's first node
    const int c4 = lane * 4;
    const unsigned w0au = h2u(We2[0 * HID + c4], We2[0 * HID + c4 + 1]);
    const unsigned w0bu = h2u(We2[0 * HID + c4 + 2], We2[0 * HID + c4 + 3]);
    const unsigned w1au = h2u(We2[1 * HID + c4], We2[1 * HID + c4 + 1]);
    const unsigned w1bu = h2u(We2[1 * HID + c4 + 2], We2[1 * HID + c4 + 3]);
    const unsigned w2au = h2u(We2[2 * HID + c4], We2[2 * HID + c4 + 1]);
    const unsigned w2bu = h2u(We2[2 * HID + c4 + 2], We2[2 * HID + c4 + 3]);
    const unsigned w3au = h2u(We2[3 * HID + c4], We2[3 * HID + c4 + 1]);
    const unsigned w3bu = h2u(We2[3 * HID + c4 + 2], We2[3 * HID + c4 + 3]);
    const unsigned w4au = h2u(We2[4 * HID + c4], We2[4 * HID + c4 + 1]);
    const unsigned w4bu = h2u(We2[4 * HID + c4 + 2], We2[4 * HID + c4 + 3]);
    const unsigned w5au = h2u(We2[5 * HID + c4], We2[5 * HID + c4 + 1]);
    const unsigned w5bu = h2u(We2[5 * HID + c4 + 2], We2[5 * HID + c4 + 3]);
    const unsigned w6au = h2u(We2[6 * HID + c4], We2[6 * HID + c4 + 1]);
    const unsigned w6bu = h2u(We2[6 * HID + c4 + 2], We2[6 * HID + c4 + 3]);
    const unsigned bb01u = h2u(be2[c4], be2[c4 + 1]);
    const unsigned bb23u = h2u(be2[c4 + 2], be2[c4 + 3]);
    const __half2 z2 = __float2half2_rn(0.f);

    uint2* ap = accs + (size_t)(w * 16) * 64 + lane;   // + j*64 per node
#pragma unroll
    for (int j = 0; j < 16; ++j) ap[j * 64] = make_uint2(0u, 0u);

    const f32x4* rp = (const f32x4*)rec;
    // clamp so the tail block's bounds loads stay inside base2
    const int njc = min(n0 + (lane & 15), N_NODES - 1);

    for (int b = 0; b < NBIN; ++b) {
        // wave's 16 segment bounds via one per-lane load pair + readlane
        int blo = base2[njc * NBIN + b];
        int bhi = base2[njc * NBIN + b + 1];

        f32x4 a0, a1, a2, a3, t0, t1, t2, t3;
        unsigned h0, h1, h2, h3, g0, g1, g2, g3;
        int s0A = __builtin_amdgcn_readlane(blo, 0);
        int s1A = __builtin_amdgcn_readlane(bhi, 0);
        SEGLOAD(a0, a1, a2, a3, h0, h1, h2, h3, s0A, s1A);
        int s0B, s1B;
        for (int j = 0; j + 1 < 16; j += 2) {
            s0B = __builtin_amdgcn_readlane(blo, j + 1);
            s1B = __builtin_amdgcn_readlane(bhi, j + 1);
            SEGLOAD(t0, t1, t2, t3, g0, g1, g2, g3, s0B, s1B);
            CONSUME(a0, a1, a2, a3, h0, h1, h2, h3, s0A, s1A, j);
            if (j + 2 < 16) {
                s0A = __builtin_amdgcn_readlane(blo, j + 2);
                s1A = __builtin_amdgcn_readlane(bhi, j + 2);
                SEGLOAD(a0, a1, a2, a3, h0, h1, h2, h3, s0A, s1A);
            }
            CONSUME(t0, t1, t2, t3, g0, g1, g2, g3, s0B, s1B, j + 1);
        }
    }
    // epilogue: self term + store
    for (int j = 0; j < 16; ++j) {
        int n = n0 + j;
        if (n >= N_NODES) break;
        uint2 p = ap[j * 64];
        __half2 acc0 = u2h(p.x), acc1 = u2h(p.y);
        unsigned hv = h8[(size_t)n * 64 + lane];
        v2f f0 = __builtin_amdgcn_cvt_pk_f32_fp8((int)hv, false);
        v2f f1 = __builtin_amdgcn_cvt_pk_f32_fp8((int)hv, true);
        acc0 = __hadd2(acc0, __float22half2_rn(make_float2(f0.x, f0.y)));
        acc1 = __hadd2(acc1, __float22half2_rn(make_float2(f1.x, f1.y)));
        float2 of;
        *(__half2*)&of.x = acc0;
        *(__half2*)&of.y = acc1;
        *(float2*)&accum[(size_t)n * HID + c4] = of;
    }
}

// ------------------------------------------------- W2 -> fp16 B-frag swizzle ---
__global__ __launch_bounds__(256) void w2_swizzle_kernel(const float* __restrict__ W,
                                                         __half* __restrict__ W2s) {
    int t = blockIdx.x * 256 + threadIdx.x;   // 16*8*64 = 8192
    if (t >= 16 * 8 * 64) return;
    int lane = t & 63;
    int kc = (t >> 6) & 7;
    int ct = t >> 9;
    int k0 = kc * 32 + (lane >> 4) * 8;
    int col = ct * 16 + (lane & 15);
#pragma unroll
    for (int j = 0; j < 8; ++j)
        W2s[(size_t)t * 8 + j] = __float2half(W[(size_t)(k0 + j) * HID + col]);
}

// ---------------------------------------------------------------- node MLP ---
template <bool FUSE_END>
__global__ __launch_bounds__(256) void node2_mfma_kernel(
        const __half* __restrict__ A,     // [N][256] fp16 (accum)
        const __half* __restrict__ W2s,   // swizzled B-frags
        const float* __restrict__ b,      // [256]
        unsigned char* __restrict__ h8,   // [N][256] fp8 out (!FUSE_END)
        const float* __restrict__ Wend,   // [256] (FUSE_END)
        const float* __restrict__ bend,   // [1]   (FUSE_END)
        float* __restrict__ out) {        // [N] (FUSE_END)
    const int lane = threadIdx.x & 63;
    const int wv = threadIdx.x >> 6;
    const int n_base = blockIdx.x * 64 + wv * 16;
    if (n_base >= N_NODES) return;
    const int quad = lane >> 4;
    const int mrow = lane & 15;
    f16x8 af[8];
    const __half* ap = A + (size_t)(n_base + mrow) * HID + quad * 8;
#pragma unroll
    for (int kc = 0; kc < 8; ++kc)
        af[kc] = *(const f16x8*)(ap + kc * 32);
    float p0 = 0.f, p1 = 0.f, p2 = 0.f, p3 = 0.f;
#pragma unroll
    for (int ct = 0; ct < 16; ++ct) {
        f32x4 c = {0.f, 0.f, 0.f, 0.f};
        const f16x8* bp = (const f16x8*)W2s + (size_t)(ct * 8) * 64 + lane;
#pragma unroll
        for (int kc = 0; kc < 8; ++kc)
            c = __builtin_amdgcn_mfma_f32_16x16x32_f16(af[kc], bp[(size_t)kc * 64],
                                                       c, 0, 0, 0);
        const int col = ct * 16 + mrow;
        const float bias = b[col];
        if (!FUSE_END) {
#pragma unroll
            for (int r = 0; r < 4; ++r) {
                int n = n_base + quad * 4 + r;
                float v = fmaxf(c[r] + bias, 0.f);
                int pk = __builtin_amdgcn_cvt_pk_fp8_f32(v, v, 0, false);
                if (n < N_NODES)
                    h8[(size_t)n * HID + col] = (unsigned char)(pk & 0xff);
            }
        } else {
            const float we = Wend[col];
            p0 = fmaf(fmaxf(c[0] + bias, 0.f), we, p0);
            p1 = fmaf(fmaxf(c[1] + bias, 0.f), we, p1);
            p2 = fmaf(fmaxf(c[2] + bias, 0.f), we, p2);
            p3 = fmaf(fmaxf(c[3] + bias, 0.f), we, p3);
        }
    }
    if (FUSE_END) {
#pragma unroll
        for (int mask = 1; mask < 16; mask <<= 1) {
            p0 += __shfl_xor(p0, mask);
            p1 += __shfl_xor(p1, mask);
            p2 += __shfl_xor(p2, mask);
            p3 += __shfl_xor(p3, mask);
        }
        if (mrow == 0) {
            const float bd = bend[0];
            int n = n_base + quad * 4;
            if (n + 0 < N_NODES) out[n + 0] = 1.f / (1.f + expf(-(p0 + bd)));
            if (n + 1 < N_NODES) out[n + 1] = 1.f / (1.f + expf(-(p1 + bd)));
            if (n + 2 < N_NODES) out[n + 2] = 1.f / (1.f + expf(-(p2 + bd)));
            if (n + 3 < N_NODES) out[n + 3] = 1.f / (1.f + expf(-(p3 + bd)));
        }
    }
}

// ------------------------------------------------------------------ launch ---
extern "C" void kernel_launch(void* const* d_in, const int* in_sizes, int n_in,
                              void* d_out, int out_size, void* d_ws, size_t ws_size,
                              hipStream_t stream) {
    const float* x    = (const float*)d_in[0];
    const int*   ei   = (const int*)d_in[1];
    const float* ea   = (const float*)d_in[2];
    const float* We1  = (const float*)d_in[3];
    const float* be1  = (const float*)d_in[4];
    const float* W1   = (const float*)d_in[5];
    const float* b1   = (const float*)d_in[6];
    const float* We2  = (const float*)d_in[7];
    const float* be2  = (const float*)d_in[8];
    const float* W2   = (const float*)d_in[9];
    const float* b2   = (const float*)d_in[10];
    const float* Wend = (const float*)d_in[11];
    const float* bend = (const float*)d_in[12];
    float* out = (float*)d_out;

    const int* src = ei;
    const int* dst = ei + N_EDGES;

    const size_t HN = (size_t)N_NODES * HID;           // 12.8M elements
    __half*   Bh   = (__half*)d_ws;                    // [N][256] fp16 accum
    unsigned* Ah   = (unsigned*)(Bh + HN);             // [N][64] fp8x4 h
    float*    rec  = (float*)(Ah + (size_t)N_NODES * 64); // [E][4] 16B records
    __half*   W2s  = (__half*)(rec + (size_t)N_EDGES * 4);
    int*   deg2    = (int*)(W2s + 16 * 8 * 64 * 8);    // [M2]
    int*   cursor2 = deg2 + M2;                        // [M2]
    int*   base2   = cursor2 + M2;                     // [M2+1]
    int*   bsum    = base2 + M2 + 1;                   // [SB2]
    // total ≈ 69 MB

    const int E4_B = (N_EDGES + 4 * 256 - 1) / (4 * 256);   // 1563

    // ---- binned CSR build + record sort (shared by all 3 layers)
    hipMemsetAsync(deg2, 0, (size_t)M2 * sizeof(int), stream);
    hist_kernel<<<E4_B, 256, 0, stream>>>(src, dst, deg2);
    scan1_kernel<<<SB2, 256, 0, stream>>>(deg2, bsum);
    scan2_kernel<<<1, 256, 0, stream>>>(bsum);
    scan3_kernel<<<SB2, 256, 0, stream>>>(deg2, bsum, base2, cursor2);
    scatter_rec_kernel<<<E4_B, 256, 0, stream>>>(src, dst, ea, cursor2, rec);
    w2_swizzle_kernel<<<32, 256, 0, stream>>>(W2, W2s);

    // ---- layer 1 (fused gather + MLP) -> Ah (fp8)
    layer1_kernel<<<(N_NODES + 3) / 4, 256, 0, stream>>>(x, rec, base2, We1, be1,
                                                         W1, b1, Ah);

    const int N2_B = (N_NODES + 63) / 64;
    // ---- layer 2
    aggr2_kernel<<<V2_GRID, 256, 0, stream>>>(Ah, rec, base2, We2, be2, Bh);
    node2_mfma_kernel<false><<<N2_B, 256, 0, stream>>>(Bh, W2s, b2,
                                                       (unsigned char*)Ah,
                                                       nullptr, nullptr, nullptr);
    // ---- layer 3 + fused head
    aggr2_kernel<<<V2_GRID, 256, 0, stream>>>(Ah, rec, base2, We2, be2, Bh);
    node2_mfma_kernel<true><<<N2_B, 256, 0, stream>>>(Bh, W2s, b2, nullptr,
                                                      Wend, bend, out);
}

// Round 8
// 534.189 us; speedup vs baseline: 2.1084x; 1.6078x over previous
//
#include <hip/hip_runtime.h>
#include <hip/hip_fp16.h>
#include <math.h>

#define N_NODES 50000
#define N_EDGES 1600000
#define HID 256
#define SCAN_B 196   // ceil(N_NODES/256)
// eps = 0

typedef _Float16 f16x8 __attribute__((ext_vector_type(8)));
typedef float f32x4 __attribute__((ext_vector_type(4)));
typedef float v2f __attribute__((ext_vector_type(2)));

// ROCm 7.2 has no __hmax2 — emit v_pk_max_f16 directly.
static __device__ __forceinline__ __half2 pk_max2(__half2 a, __half2 b) {
    unsigned au = *reinterpret_cast<unsigned*>(&a);
    unsigned bu = *reinterpret_cast<unsigned*>(&b);
    unsigned r;
    asm("v_pk_max_f16 %0, %1, %2" : "=v"(r) : "v"(au), "v"(bu));
    return *reinterpret_cast<__half2*>(&r);
}

// 4 floats -> 4 fp8 (e4m3) packed in one dword
static __device__ __forceinline__ unsigned pack4_fp8(float a, float b, float c, float d) {
    int v = __builtin_amdgcn_cvt_pk_fp8_f32(a, b, 0, false);
    v = __builtin_amdgcn_cvt_pk_fp8_f32(c, d, v, true);
    return (unsigned)v;
}

// ---------------------------------------------------------------- CSR build ---
// 4 edges per thread (strided) — keeps 4 independent memory chains in flight.
__global__ __launch_bounds__(256) void hist_kernel(const int* __restrict__ dst,
                                                   int* __restrict__ deg) {
    const int T = gridDim.x * 256;
    const int t = blockIdx.x * 256 + threadIdx.x;
#pragma unroll
    for (int i = 0; i < 4; ++i) {
        int e = t + i * T;
        if (e < N_EDGES) atomicAdd(&deg[dst[e]], 1);   // no return use: fire&forget
    }
}

__global__ __launch_bounds__(256) void scan1_kernel(const int* __restrict__ deg,
                                                    int* __restrict__ bsum) {
    int idx = blockIdx.x * 256 + threadIdx.x;
    int v = (idx < N_NODES) ? deg[idx] : 0;
#pragma unroll
    for (int off = 32; off > 0; off >>= 1) v += __shfl_down(v, off);
    __shared__ int ws[4];
    if ((threadIdx.x & 63) == 0) ws[threadIdx.x >> 6] = v;
    __syncthreads();
    if (threadIdx.x == 0) bsum[blockIdx.x] = ws[0] + ws[1] + ws[2] + ws[3];
}

__global__ __launch_bounds__(256) void scan2_kernel(int* __restrict__ bsum) {
    __shared__ int s[256];
    int t = threadIdx.x;
    int v = (t < SCAN_B) ? bsum[t] : 0;
    s[t] = v;
    __syncthreads();
    for (int off = 1; off < 256; off <<= 1) {
        int u = (t >= off) ? s[t - off] : 0;
        __syncthreads();
        s[t] += u;
        __syncthreads();
    }
    if (t < SCAN_B) bsum[t] = s[t] - v;  // exclusive
}

// also pre-initializes cursor = base, so scatter needs a single atomicAdd
__global__ __launch_bounds__(256) void scan3_kernel(const int* __restrict__ deg,
                                                    const int* __restrict__ bsum,
                                                    int* __restrict__ base,
                                                    int* __restrict__ cursor) {
    __shared__ int s[256];
    int t = threadIdx.x;
    int idx = blockIdx.x * 256 + t;
    int v = (idx < N_NODES) ? deg[idx] : 0;
    s[t] = v;
    __syncthreads();
    for (int off = 1; off < 256; off <<= 1) {
        int u = (t >= off) ? s[t - off] : 0;
        __syncthreads();
        s[t] += u;
        __syncthreads();
    }
    if (idx < N_NODES) {
        int bv = bsum[blockIdx.x] + s[t] - v;
        base[idx] = bv;
        cursor[idx] = bv;
    }
    if (idx == 0) base[N_NODES] = N_EDGES;
}

// build one dst-sorted 32B record {half2(a0,a0)..half2(a6,a6), src_bits}
static __device__ __forceinline__ void write_rec(float* __restrict__ rec, int pos,
                                                 const float* __restrict__ ep, int s) {
    float4 v0, v1;
    *(__half2*)&v0.x = __floats2half2_rn(ep[0], ep[0]);
    *(__half2*)&v0.y = __floats2half2_rn(ep[1], ep[1]);
    *(__half2*)&v0.z = __floats2half2_rn(ep[2], ep[2]);
    *(__half2*)&v0.w = __floats2half2_rn(ep[3], ep[3]);
    *(__half2*)&v1.x = __floats2half2_rn(ep[4], ep[4]);
    *(__half2*)&v1.y = __floats2half2_rn(ep[5], ep[5]);
    *(__half2*)&v1.z = __floats2half2_rn(ep[6], ep[6]);
    v1.w = __int_as_float(s);
    float* rp = rec + (size_t)pos * 8;
    *(float4*)rp       = v0;
    *(float4*)(rp + 4) = v1;
}

// 4 edges per thread (strided): 4 independent atomic round-trips + 4 record
// stores in flight. e0..e2 always valid at this grid size; e3 guarded.
// cursor pre-initialized to base: pos = atomicAdd(&cursor[d],1) directly.
__global__ __launch_bounds__(256) void scatter_rec_kernel(
        const int* __restrict__ src,
        const int* __restrict__ dst,
        const float* __restrict__ ea,
        int* __restrict__ cursor,
        float* __restrict__ rec) {
    const int T = gridDim.x * 256;
    const int t = blockIdx.x * 256 + threadIdx.x;
    const int e0 = t, e1 = t + T, e2 = t + 2 * T, e3 = t + 3 * T;
    const bool v3 = (e3 < N_EDGES);
    int d0 = dst[e0], d1 = dst[e1], d2 = dst[e2];
    int s0 = src[e0], s1 = src[e1], s2 = src[e2];
    int d3 = v3 ? dst[e3] : 0;
    int s3 = v3 ? src[e3] : 0;
    int p0 = atomicAdd(&cursor[d0], 1);
    int p1 = atomicAdd(&cursor[d1], 1);
    int p2 = atomicAdd(&cursor[d2], 1);
    int p3 = v3 ? atomicAdd(&cursor[d3], 1) : 0;
    write_rec(rec, p0, ea + (size_t)e0 * 7, s0);
    write_rec(rec, p1, ea + (size_t)e1 * 7, s1);
    write_rec(rec, p2, ea + (size_t)e2 * 7, s2);
    if (v3) write_rec(rec, p3, ea + (size_t)e3 * 7, s3);
}

// ---------------------------------------------------------------- layer 1 ---
// fused gather + node MLP; writes h as fp8 (one dword = lane's 4 channels)
__global__ __launch_bounds__(256) void layer1_kernel(
        const float* __restrict__ x,     // [N][2]
        const float* __restrict__ rec,   // [E][8] (ea as dup'd half2)
        const int* __restrict__ base,    // [N+1]
        const float* __restrict__ We1,   // [7][2]
        const float* __restrict__ be1,   // [2]
        const float* __restrict__ W1,    // [2][256]
        const float* __restrict__ b1,    // [256]
        unsigned* __restrict__ h8) {     // [N][64] dwords (fp8 x4)
    const int lane = threadIdx.x & 63;
    const int wid = threadIdx.x >> 6;
    const int n = blockIdx.x * 4 + wid;
    if (n >= N_NODES) return;
    float w00 = We1[0],  w01 = We1[1],  w10 = We1[2],  w11 = We1[3];
    float w20 = We1[4],  w21 = We1[5],  w30 = We1[6],  w31 = We1[7];
    float w40 = We1[8],  w41 = We1[9],  w50 = We1[10], w51 = We1[11];
    float w60 = We1[12], w61 = We1[13];
    float bb0 = be1[0], bb1 = be1[1];
    float m0 = 0.f, m1 = 0.f;
    const int s0 = base[n], s1 = base[n + 1];
    for (int pos = s0 + lane; pos < s1; pos += 64) {
        const float* p = rec + (size_t)pos * 8;
        float4 a = *(const float4*)p;
        float4 b = *(const float4*)(p + 4);
        int s = __float_as_int(b.w);
        float a0 = __low2float(*(__half2*)&a.x);
        float a1 = __low2float(*(__half2*)&a.y);
        float a2 = __low2float(*(__half2*)&a.z);
        float a3 = __low2float(*(__half2*)&a.w);
        float a4 = __low2float(*(__half2*)&b.x);
        float a5 = __low2float(*(__half2*)&b.y);
        float a6 = __low2float(*(__half2*)&b.z);
        float t0 = bb0, t1 = bb1;
        t0 = fmaf(a0, w00, t0); t1 = fmaf(a0, w01, t1);
        t0 = fmaf(a1, w10, t0); t1 = fmaf(a1, w11, t1);
        t0 = fmaf(a2, w20, t0); t1 = fmaf(a2, w21, t1);
        t0 = fmaf(a3, w30, t0); t1 = fmaf(a3, w31, t1);
        t0 = fmaf(a4, w40, t0); t1 = fmaf(a4, w41, t1);
        t0 = fmaf(a5, w50, t0); t1 = fmaf(a5, w51, t1);
        t0 = fmaf(a6, w60, t0); t1 = fmaf(a6, w61, t1);
        float2 xv = *(const float2*)&x[(size_t)s * 2];
        m0 += fmaxf(t0 + xv.x, 0.f);
        m1 += fmaxf(t1 + xv.y, 0.f);
    }
#pragma unroll
    for (int off = 32; off > 0; off >>= 1) {
        m0 += __shfl_down(m0, off);
        m1 += __shfl_down(m1, off);
    }
    m0 = __shfl(m0, 0);
    m1 = __shfl(m1, 0);
    const float t0 = x[n * 2 + 0] + m0;
    const float t1 = x[n * 2 + 1] + m1;
    const int c = lane * 4;
    float4 wa = *(const float4*)&W1[c];
    float4 wb = *(const float4*)&W1[256 + c];
    float4 bv = *(const float4*)&b1[c];
    float4 r;
    r.x = fmaxf(fmaf(t0, wa.x, fmaf(t1, wb.x, bv.x)), 0.f);
    r.y = fmaxf(fmaf(t0, wa.y, fmaf(t1, wb.y, bv.y)), 0.f);
    r.z = fmaxf(fmaf(t0, wa.z, fmaf(t1, wb.z, bv.z)), 0.f);
    r.w = fmaxf(fmaf(t0, wa.w, fmaf(t1, wb.w, bv.w)), 0.f);
    h8[(size_t)n * 64 + lane] = pack4_fp8(r.x, r.y, r.z, r.w);
}

// ------------------------------------------------------------ layers 2..3 ---
// CSR gather from fp8 h (1 dword = 4 channels/lane), packed-fp16 edge MLP,
// fp16 accumulate. One wave/node; ping-pong, 4 edges/group, 8 h-loads in flight.
#define EDGEH(RA, RB, HU)                                              \
    do {                                                               \
        __half2 _a0 = *(__half2*)&RA.x, _a1 = *(__half2*)&RA.y;        \
        __half2 _a2 = *(__half2*)&RA.z, _a3 = *(__half2*)&RA.w;        \
        __half2 _a4 = *(__half2*)&RB.x, _a5 = *(__half2*)&RB.y;        \
        __half2 _a6 = *(__half2*)&RB.z;                                \
        __half2 _m0 = bb01, _m1 = bb23;                                \
        _m0 = __hfma2(_a0, w0a, _m0); _m1 = __hfma2(_a0, w0b, _m1);    \
        _m0 = __hfma2(_a1, w1a, _m0); _m1 = __hfma2(_a1, w1b, _m1);    \
        _m0 = __hfma2(_a2, w2a, _m0); _m1 = __hfma2(_a2, w2b, _m1);    \
        _m0 = __hfma2(_a3, w3a, _m0); _m1 = __hfma2(_a3, w3b, _m1);    \
        _m0 = __hfma2(_a4, w4a, _m0); _m1 = __hfma2(_a4, w4b, _m1);    \
        _m0 = __hfma2(_a5, w5a, _m0); _m1 = __hfma2(_a5, w5b, _m1);    \
        _m0 = __hfma2(_a6, w6a, _m0); _m1 = __hfma2(_a6, w6b, _m1);    \
        v2f _hf0 = __builtin_amdgcn_cvt_pk_f32_fp8((int)(HU), false);  \
        v2f _hf1 = __builtin_amdgcn_cvt_pk_f32_fp8((int)(HU), true);   \
        __half2 _h0 = __float22half2_rn(make_float2(_hf0.x, _hf0.y));  \
        __half2 _h1 = __float22half2_rn(make_float2(_hf1.x, _hf1.y));  \
        _m0 = pk_max2(__hadd2(_m0, _h0), z2);                          \
        _m1 = pk_max2(__hadd2(_m1, _h1), z2);                          \
        acc0 = __hadd2(acc0, _m0);                                     \
        acc1 = __hadd2(acc1, _m1);                                     \
    } while (0)

#define HLOAD(RB) (h8[(size_t)__builtin_amdgcn_readfirstlane(          \
                       __float_as_int(RB.w)) * 64 + lane])

#define LOADG(A0, B0, A1, B1, A2, B2, A3, B3, H0, H1, H2, H3, G)       \
    do {                                                               \
        const float4* _rp = rp + (size_t)(G) * 8;                      \
        A0 = _rp[0]; B0 = _rp[1]; A1 = _rp[2]; B1 = _rp[3];            \
        A2 = _rp[4]; B2 = _rp[5]; A3 = _rp[6]; B3 = _rp[7];            \
        H0 = HLOAD(B0); H1 = HLOAD(B1);                                \
        H2 = HLOAD(B2); H3 = HLOAD(B3);                                \
    } while (0)

#define CONS4(A0, B0, A1, B1, A2, B2, A3, B3, H0, H1, H2, H3)          \
    do {                                                               \
        EDGEH(A0, B0, H0); EDGEH(A1, B1, H1);                          \
        EDGEH(A2, B2, H2); EDGEH(A3, B3, H3);                          \
    } while (0)

__global__ __launch_bounds__(256) void aggr2_kernel(
        const unsigned* __restrict__ h8,  // [N][64] dwords (fp8 x4)
        const float* __restrict__ rec,    // [E][8] dst-sorted packed records
        const int* __restrict__ base,     // [N+1]
        const float* __restrict__ We2,    // [7][256] fp32
        const float* __restrict__ be2,    // [256] fp32
        __half* __restrict__ accum) {     // [N][256] fp16 out
    const int lane = threadIdx.x & 63;
    const int n = blockIdx.x * 4 + (threadIdx.x >> 6);
    if (n >= N_NODES) return;
    const int c4 = lane * 4;
    __half2 w0a = __floats2half2_rn(We2[0 * HID + c4], We2[0 * HID + c4 + 1]);
    __half2 w0b = __floats2half2_rn(We2[0 * HID + c4 + 2], We2[0 * HID + c4 + 3]);
    __half2 w1a = __floats2half2_rn(We2[1 * HID + c4], We2[1 * HID + c4 + 1]);
    __half2 w1b = __floats2half2_rn(We2[1 * HID + c4 + 2], We2[1 * HID + c4 + 3]);
    __half2 w2a = __floats2half2_rn(We2[2 * HID + c4], We2[2 * HID + c4 + 1]);
    __half2 w2b = __floats2half2_rn(We2[2 * HID + c4 + 2], We2[2 * HID + c4 + 3]);
    __half2 w3a = __floats2half2_rn(We2[3 * HID + c4], We2[3 * HID + c4 + 1]);
    __half2 w3b = __floats2half2_rn(We2[3 * HID + c4 + 2], We2[3 * HID + c4 + 3]);
    __half2 w4a = __floats2half2_rn(We2[4 * HID + c4], We2[4 * HID + c4 + 1]);
    __half2 w4b = __floats2half2_rn(We2[4 * HID + c4 + 2], We2[4 * HID + c4 + 3]);
    __half2 w5a = __floats2half2_rn(We2[5 * HID + c4], We2[5 * HID + c4 + 1]);
    __half2 w5b = __floats2half2_rn(We2[5 * HID + c4 + 2], We2[5 * HID + c4 + 3]);
    __half2 w6a = __floats2half2_rn(We2[6 * HID + c4], We2[6 * HID + c4 + 1]);
    __half2 w6b = __floats2half2_rn(We2[6 * HID + c4 + 2], We2[6 * HID + c4 + 3]);
    __half2 bb01 = __floats2half2_rn(be2[c4], be2[c4 + 1]);
    __half2 bb23 = __floats2half2_rn(be2[c4 + 2], be2[c4 + 3]);
    const __half2 z2 = __float2half2_rn(0.f);

    // acc init = h[n] (fp8 -> fp16)
    __half2 acc0, acc1;
    {
        unsigned hv = h8[(size_t)n * 64 + lane];
        v2f f0 = __builtin_amdgcn_cvt_pk_f32_fp8((int)hv, false);
        v2f f1 = __builtin_amdgcn_cvt_pk_f32_fp8((int)hv, true);
        acc0 = __float22half2_rn(make_float2(f0.x, f0.y));
        acc1 = __float22half2_rn(make_float2(f1.x, f1.y));
    }
    const int s0 = __builtin_amdgcn_readfirstlane(base[n]);
    const int deg = __builtin_amdgcn_readfirstlane(base[n + 1]) - s0;
    const float4* rp = (const float4*)rec + (size_t)s0 * 2;
    const int ng = deg >> 2;

    float4 r0a, r0b, r1a, r1b, r2a, r2b, r3a, r3b;
    unsigned rh0, rh1, rh2, rh3;
    float4 t0a, t0b, t1a, t1b, t2a, t2b, t3a, t3b;
    unsigned th0, th1, th2, th3;

    if (ng > 0) {
        LOADG(r0a, r0b, r1a, r1b, r2a, r2b, r3a, r3b, rh0, rh1, rh2, rh3, 0);
        int g = 1;
        for (; g + 1 < ng; g += 2) {
            LOADG(t0a, t0b, t1a, t1b, t2a, t2b, t3a, t3b, th0, th1, th2, th3, g);
            CONS4(r0a, r0b, r1a, r1b, r2a, r2b, r3a, r3b, rh0, rh1, rh2, rh3);
            LOADG(r0a, r0b, r1a, r1b, r2a, r2b, r3a, r3b, rh0, rh1, rh2, rh3, g + 1);
            CONS4(t0a, t0b, t1a, t1b, t2a, t2b, t3a, t3b, th0, th1, th2, th3);
        }
        if (g < ng) {
            LOADG(t0a, t0b, t1a, t1b, t2a, t2b, t3a, t3b, th0, th1, th2, th3, g);
            CONS4(r0a, r0b, r1a, r1b, r2a, r2b, r3a, r3b, rh0, rh1, rh2, rh3);
            CONS4(t0a, t0b, t1a, t1b, t2a, t2b, t3a, t3b, th0, th1, th2, th3);
        } else {
            CONS4(r0a, r0b, r1a, r1b, r2a, r2b, r3a, r3b, rh0, rh1, rh2, rh3);
        }
    }
    for (int i = ng * 4; i < deg; ++i) {   // remainder 0..3 edges
        float4 ra = rp[(size_t)i * 2], rbv = rp[(size_t)i * 2 + 1];
        unsigned hv = HLOAD(rbv);
        EDGEH(ra, rbv, hv);
    }
    float2 of;
    *(__half2*)&of.x = acc0;
    *(__half2*)&of.y = acc1;
    *(float2*)&accum[(size_t)n * HID + c4] = of;
}

// ------------------------------------------------- W2 -> fp16 B-frag swizzle ---
// W2s[((ct*8+kc)*64+lane)*8 + j] = W2[kc*32 + (lane>>4)*8 + j][ct*16 + (lane&15)]
__global__ __launch_bounds__(256) void w2_swizzle_kernel(const float* __restrict__ W,
                                                         __half* __restrict__ W2s) {
    int t = blockIdx.x * 256 + threadIdx.x;   // 16*8*64 = 8192
    if (t >= 16 * 8 * 64) return;
    int lane = t & 63;
    int kc = (t >> 6) & 7;
    int ct = t >> 9;
    int k0 = kc * 32 + (lane >> 4) * 8;
    int col = ct * 16 + (lane & 15);
#pragma unroll
    for (int j = 0; j < 8; ++j)
        W2s[(size_t)t * 8 + j] = __float2half(W[(size_t)(k0 + j) * HID + col]);
}

// ---------------------------------------------------------------- node MLP ---
// relu(A @ W2 + b2) via mfma_f32_16x16x32_f16.
// FUSE_END=false: write h as fp8. FUSE_END=true: fuse the sigmoid head.
template <bool FUSE_END>
__global__ __launch_bounds__(256) void node2_mfma_kernel(
        const __half* __restrict__ A,     // [N][256] fp16 (accum)
        const __half* __restrict__ W2s,   // swizzled B-frags
        const float* __restrict__ b,      // [256]
        unsigned char* __restrict__ h8,   // [N][256] fp8 out (!FUSE_END)
        const float* __restrict__ Wend,   // [256] (FUSE_END)
        const float* __restrict__ bend,   // [1]   (FUSE_END)
        float* __restrict__ out) {        // [N] (FUSE_END)
    const int lane = threadIdx.x & 63;
    const int wv = threadIdx.x >> 6;
    const int n_base = blockIdx.x * 64 + wv * 16;
    if (n_base >= N_NODES) return;
    const int quad = lane >> 4;
    const int mrow = lane & 15;
    // A-frags for all 8 k-chunks: A[m=lane&15][k=quad*8+j]
    f16x8 af[8];
    const __half* ap = A + (size_t)(n_base + mrow) * HID + quad * 8;
#pragma unroll
    for (int kc = 0; kc < 8; ++kc)
        af[kc] = *(const f16x8*)(ap + kc * 32);
    float p0 = 0.f, p1 = 0.f, p2 = 0.f, p3 = 0.f;   // head partials (FUSE_END)
#pragma unroll
    for (int ct = 0; ct < 16; ++ct) {
        f32x4 c = {0.f, 0.f, 0.f, 0.f};
        const f16x8* bp = (const f16x8*)W2s + (size_t)(ct * 8) * 64 + lane;
#pragma unroll
        for (int kc = 0; kc < 8; ++kc)
            c = __builtin_amdgcn_mfma_f32_16x16x32_f16(af[kc], bp[(size_t)kc * 64],
                                                       c, 0, 0, 0);
        const int col = ct * 16 + mrow;            // D col = lane&15
        const float bias = b[col];
        if (!FUSE_END) {
#pragma unroll
            for (int r = 0; r < 4; ++r) {          // D row = quad*4 + r
                int n = n_base + quad * 4 + r;
                float v = fmaxf(c[r] + bias, 0.f);
                int pk = __builtin_amdgcn_cvt_pk_fp8_f32(v, v, 0, false);
                if (n < N_NODES)
                    h8[(size_t)n * HID + col] = (unsigned char)(pk & 0xff);
            }
        } else {
            const float we = Wend[col];
            p0 = fmaf(fmaxf(c[0] + bias, 0.f), we, p0);
            p1 = fmaf(fmaxf(c[1] + bias, 0.f), we, p1);
            p2 = fmaf(fmaxf(c[2] + bias, 0.f), we, p2);
            p3 = fmaf(fmaxf(c[3] + bias, 0.f), we, p3);
        }
    }
    if (FUSE_END) {
        // reduce over the 16 mrow lanes of each quad group
#pragma unroll
        for (int mask = 1; mask < 16; mask <<= 1) {
            p0 += __shfl_xor(p0, mask);
            p1 += __shfl_xor(p1, mask);
            p2 += __shfl_xor(p2, mask);
            p3 += __shfl_xor(p3, mask);
        }
        if (mrow == 0) {
            const float bd = bend[0];
            int n = n_base + quad * 4;
            if (n + 0 < N_NODES) out[n + 0] = 1.f / (1.f + expf(-(p0 + bd)));
            if (n + 1 < N_NODES) out[n + 1] = 1.f / (1.f + expf(-(p1 + bd)));
            if (n + 2 < N_NODES) out[n + 2] = 1.f / (1.f + expf(-(p2 + bd)));
            if (n + 3 < N_NODES) out[n + 3] = 1.f / (1.f + expf(-(p3 + bd)));
        }
    }
}

// ------------------------------------------------------------------ launch ---
extern "C" void kernel_launch(void* const* d_in, const int* in_sizes, int n_in,
                              void* d_out, int out_size, void* d_ws, size_t ws_size,
                              hipStream_t stream) {
    const float* x    = (const float*)d_in[0];
    const int*   ei   = (const int*)d_in[1];
    const float* ea   = (const float*)d_in[2];
    const float* We1  = (const float*)d_in[3];
    const float* be1  = (const float*)d_in[4];
    const float* W1   = (const float*)d_in[5];
    const float* b1   = (const float*)d_in[6];
    const float* We2  = (const float*)d_in[7];
    const float* be2  = (const float*)d_in[8];
    const float* W2   = (const float*)d_in[9];
    const float* b2   = (const float*)d_in[10];
    const float* Wend = (const float*)d_in[11];
    const float* bend = (const float*)d_in[12];
    float* out = (float*)d_out;

    const int* src = ei;
    const int* dst = ei + N_EDGES;

    const size_t HN = (size_t)N_NODES * HID;           // 12.8M elements
    __half*   Bh   = (__half*)d_ws;                    // [N][256] fp16 accum
    unsigned* Ah   = (unsigned*)(Bh + HN);             // [N][64] fp8x4 h
    float*    rec  = (float*)(Ah + (size_t)N_NODES * 64); // [E][8]
    __half*   W2s  = (__half*)(rec + (size_t)N_EDGES * 8);
    int*   deg    = (int*)(W2s + 16 * 8 * 64 * 8);     // [N]
    int*   cursor = deg + N_NODES;                     // [N]
    int*   base   = cursor + N_NODES;                  // [N+2]
    int*   bsum   = base + N_NODES + 2;                // [256]
    // total ≈ 90 MB

    const int E4_B = (N_EDGES + 4 * 256 - 1) / (4 * 256);   // 1563

    // ---- CSR build + record sort (shared by all 3 layers)
    hipMemsetAsync(deg, 0, (size_t)N_NODES * sizeof(int), stream);
    hist_kernel<<<E4_B, 256, 0, stream>>>(dst, deg);
    scan1_kernel<<<SCAN_B, 256, 0, stream>>>(deg, bsum);
    scan2_kernel<<<1, 256, 0, stream>>>(bsum);
    scan3_kernel<<<SCAN_B, 256, 0, stream>>>(deg, bsum, base, cursor);
    scatter_rec_kernel<<<E4_B, 256, 0, stream>>>(src, dst, ea, cursor, rec);
    w2_swizzle_kernel<<<32, 256, 0, stream>>>(W2, W2s);

    // ---- layer 1 (fused gather + MLP) -> Ah (fp8)
    layer1_kernel<<<(N_NODES + 3) / 4, 256, 0, stream>>>(x, rec, base, We1, be1,
                                                         W1, b1, Ah);

    const int N2_B = (N_NODES + 63) / 64;
    // ---- layer 2
    aggr2_kernel<<<(N_NODES + 3) / 4, 256, 0, stream>>>(Ah, rec, base, We2, be2, Bh);
    node2_mfma_kernel<false><<<N2_B, 256, 0, stream>>>(Bh, W2s, b2,
                                                       (unsigned char*)Ah,
                                                       nullptr, nullptr, nullptr);
    // ---- layer 3 + fused head
    aggr2_kernel<<<(N_NODES + 3) / 4, 256, 0, stream>>>(Ah, rec, base, We2, be2, Bh);
    node2_mfma_kernel<true><<<N2_B, 256, 0, stream>>>(Bh, W2s, b2, nullptr,
                                                      Wend, bend, out);
}